// Round 11
// baseline (291.030 us; speedup 1.0000x reference)
//
#include <hip/hip_runtime.h>
#include <hip/hip_bf16.h>
#include <cstdint>

typedef unsigned short u16;
typedef __attribute__((ext_vector_type(8))) short bf16x8;
typedef __attribute__((ext_vector_type(4))) float f32x4;

#define BATCH 4
#define CDIM 256
#define NTOK 4096   // H*W

__device__ inline float fexp2(float x) { return __builtin_amdgcn_exp2f(x); }

__device__ inline u16 f2bf(float f) {
  union { float f; uint32_t u; } un; un.f = f;
  uint32_t u = un.u;
  u += 0x7fffu + ((u >> 16) & 1u);
  return (u16)(u >> 16);
}
__device__ inline float bf2f(u16 h) {
  union { uint32_t u; float f; } un; un.u = ((uint32_t)h) << 16; return un.f;
}

__device__ inline void gload_lds16(const u16* g, u16* l) {
  __builtin_amdgcn_global_load_lds((const __attribute__((address_space(1))) void*)g,
                                   (__attribute__((address_space(3))) void*)l, 16, 0, 0);
}

// lgkm-only barrier (R6-proven): drains LDS ops, NOT vmcnt -> staging
// global_load_lds issued before it stays in flight across the barrier.
__device__ inline void barrier_lgkm() {
  asm volatile("s_waitcnt lgkmcnt(0)\n\ts_barrier" ::: "memory");
  __builtin_amdgcn_sched_barrier(0);
}

// ---------------------------------------------------------------------------
// LayerNorm: x [B, C, N] -> xn bf16 [B*N, C]
// ---------------------------------------------------------------------------
__global__ __launch_bounds__(256) void ln_kernel(const float* __restrict__ x,
                                                 const float* __restrict__ gamma,
                                                 const float* __restrict__ beta,
                                                 u16* __restrict__ xn) {
  __shared__ float tile[CDIM][33];
  __shared__ float reds[8][32];
  __shared__ float reds2[8][32];
  __shared__ float mu_s[32], rs_s[32];

  int b  = blockIdx.x >> 7;
  int n0 = (blockIdx.x & 127) * 32;
  const float* xb = x + (size_t)b * CDIM * NTOK;

  int t = threadIdx.x & 31;
  int g = threadIdx.x >> 5;

  for (int c = g; c < CDIM; c += 8)
    tile[c][t] = xb[(size_t)c * NTOK + n0 + t];
  __syncthreads();

  float s = 0.f, s2 = 0.f;
  for (int c = g * 32; c < g * 32 + 32; ++c) {
    float v = tile[c][t];
    s += v; s2 += v * v;
  }
  reds[g][t] = s; reds2[g][t] = s2;
  __syncthreads();
  if (threadIdx.x < 32) {
    float ts = 0.f, ts2 = 0.f;
    for (int gg = 0; gg < 8; ++gg) { ts += reds[gg][threadIdx.x]; ts2 += reds2[gg][threadIdx.x]; }
    float mu = ts / CDIM;
    float var = ts2 / CDIM - mu * mu;
    mu_s[threadIdx.x] = mu;
    rs_s[threadIdx.x] = rsqrtf(var + 1e-5f);
  }
  __syncthreads();

  int c = threadIdx.x;
  float gam = gamma[c], bet = beta[c];
  u16* out = xn + ((size_t)b * NTOK + n0) * CDIM;
  for (int tt = 0; tt < 32; ++tt) {
    float v = tile[c][tt];
    float y = (v - mu_s[tt]) * rs_s[tt] * gam + bet;
    out[(size_t)tt * CDIM + c] = f2bf(y);
  }
}

// ---------------------------------------------------------------------------
// W [K, Cout] fp32 -> WT bf16 [Cout, K]; blockIdx.z selects Wq/Wk/Wv
// (Wq pre-scaled by log2e -> exp2-domain S). One launch instead of three.
// ---------------------------------------------------------------------------
__global__ __launch_bounds__(256) void wt3_kernel(const float* __restrict__ Wq,
                                                  const float* __restrict__ Wk,
                                                  const float* __restrict__ Wv,
                                                  u16* __restrict__ WT) {
  __shared__ float tile[32][33];
  int z = blockIdx.z;
  const float* W = (z == 0) ? Wq : ((z == 1) ? Wk : Wv);
  float scale = (z == 0) ? 1.4426950408889634f : 1.0f;
  u16* dst = WT + (size_t)z * CDIM * CDIM;

  int i0 = blockIdx.y * 32;
  int j0 = blockIdx.x * 32;
  int tx = threadIdx.x, ty = threadIdx.y;
  for (int r = ty; r < 32; r += 8)
    tile[r][tx] = W[(size_t)(i0 + r) * CDIM + j0 + tx];
  __syncthreads();
  for (int r = ty; r < 32; r += 8)
    dst[(size_t)(j0 + r) * CDIM + i0 + tx] = f2bf(tile[tx][r] * scale);
}

// ---------------------------------------------------------------------------
// Fused QKV projection (unchanged)
// ---------------------------------------------------------------------------
__global__ __launch_bounds__(256) void qkv_kernel(const u16* __restrict__ A,
                                                  const u16* __restrict__ B3,
                                                  u16* __restrict__ Qb,
                                                  u16* __restrict__ Kb,
                                                  u16* __restrict__ VT) {
  constexpr int BM = 128, BN = 64, BK = 32;
  __shared__ u16 shA[BM][BK + 8];
  __shared__ u16 shB[BN][BK + 8];

  int m0 = blockIdx.y * BM;
  int n0 = blockIdx.x * BN;

  int tid  = threadIdx.x;
  int lane = tid & 63;
  int wave = tid >> 6;
  int wm = wave >> 1, wn = wave & 1;
  int col  = lane & 15;
  int quad = lane >> 4;

  f32x4 acc[4][2];
#pragma unroll
  for (int i = 0; i < 4; ++i)
#pragma unroll
    for (int j = 0; j < 2; ++j) acc[i][j] = (f32x4){0.f, 0.f, 0.f, 0.f};

  for (int kb = 0; kb < CDIM; kb += BK) {
    __syncthreads();
#pragma unroll
    for (int c = tid; c < BM * BK / 8; c += 256) {
      int row = c >> 2, kc = c & 3;
      *(uint4*)&shA[row][kc * 8] = *(const uint4*)&A[(size_t)(m0 + row) * CDIM + kb + kc * 8];
    }
#pragma unroll
    for (int c = tid; c < BN * BK / 8; c += 256) {
      int row = c >> 2, kc = c & 3;
      *(uint4*)&shB[row][kc * 8] = *(const uint4*)&B3[(size_t)(n0 + row) * CDIM + kb + kc * 8];
    }
    __syncthreads();

    bf16x8 af[4], bfv[2];
#pragma unroll
    for (int i = 0; i < 4; ++i)
      af[i] = *(const bf16x8*)&shA[wm * 64 + i * 16 + col][quad * 8];
#pragma unroll
    for (int j = 0; j < 2; ++j)
      bfv[j] = *(const bf16x8*)&shB[wn * 32 + j * 16 + col][quad * 8];
#pragma unroll
    for (int i = 0; i < 4; ++i)
#pragma unroll
      for (int j = 0; j < 2; ++j)
        acc[i][j] = __builtin_amdgcn_mfma_f32_16x16x32_bf16(af[i], bfv[j], acc[i][j], 0, 0, 0);
  }

  int mode = n0 >> 8;   // 0:Q 1:K 2:V (block-uniform)
  int r0 = quad * 4;
#pragma unroll
  for (int i = 0; i < 4; ++i) {
    int mbase = m0 + wm * 64 + i * 16 + r0;
#pragma unroll
    for (int j = 0; j < 2; ++j) {
      int n = n0 + wn * 32 + j * 16 + col;
#pragma unroll
      for (int r = 0; r < 4; ++r) {
        int m = mbase + r;
        float v = acc[i][j][r];
        if (mode == 0) {
          Qb[(size_t)m * CDIM + n] = f2bf(v);
        } else if (mode == 1) {
          Kb[(size_t)m * CDIM + (n - 256)] = f2bf(v);
        } else {
          int cv = n - 512, bb = m >> 12, nt = m & 4095;
          VT[((size_t)bb * CDIM + cv) * NTOK + nt] = f2bf(v);
        }
      }
    }
  }
}

// ---------------------------------------------------------------------------
// Fused attention, ONE-PASS fixed-shift softmax (R10-verified math),
// KVBLK=64: 64-key tiles -> 64 main iterations (vs R10's 128). Per-iteration
// cost has been ~1.1-1.3us across all structures (R0-R10), insensitive to
// content; iteration count is the proven lever (192->128 gave -20%).
// Single-buffered P with mid-iteration lgkm-only barrier (staging loads fly
// across it); end __syncthreads guards staging drain + P/K/V buffer reuse.
// Role-split loops (R10-proven, spill-free); barrier counts match 1:1.
// LDS 150,016 B: k2a@0 k2b@32768 ([64][256]), v2a@65536 v2b@98304
// ([256][64]), p1@131072 p2@140288 ([64][72] u16, 144B rows: 16B-aligned,
// 2-way banks), lmerge@149504. otile [256][68] f32 overlays @0 at epilogue.
// ---------------------------------------------------------------------------

__global__ __launch_bounds__(512, 1) void fa_kernel(const u16* __restrict__ Qg,
                                                    const u16* __restrict__ Kg,
                                                    const u16* __restrict__ Vtg,
                                                    const u16* __restrict__ xng,
                                                    const float* __restrict__ w1p,
                                                    const float* __restrict__ w2p,
                                                    float* __restrict__ outg) {
  __shared__ __align__(16) char smem[150016];
  float* otile = (float*)smem;
  u16* p1 = (u16*)(smem + 131072);          // [64][72] u16
  u16* p2 = (u16*)(smem + 140288);
  float* lmerge = (float*)(smem + 149504);  // [2 kh][64 q]

  int b  = blockIdx.x & 3;               // XCD swizzle: same XCD -> same batch
  int q0 = (blockIdx.x >> 2) * 64;

  const u16* Q  = Qg  + (size_t)b * NTOK * CDIM;
  const u16* K  = Kg  + (size_t)b * NTOK * CDIM;
  const u16* Vt = Vtg + (size_t)b * NTOK * CDIM;

  int tid  = threadIdx.x;
  int lane = tid & 63;
  int w    = tid >> 6;
  int col = lane & 15, quad = lane >> 4;

  int qh = w >> 2;                 // q-half (rows qh*32 .. +32)
  bool isProd = (w & 2) == 0;      // producers: waves 0,1,4,5 (wave-uniform)
  int kh = w & 1;                  // producer key half (32 keys of 64)
  int c4 = (w & 1) + 2 * (w >> 2); // consumer channel quarter

  float e1 = __expf(w1p[0]), e2 = __expf(w2p[0]);
  float a1 = e1 / (e1 + e2), a2 = e2 / (e1 + e2);
  float a2p = a2 * 0.4804530139182014f;  // a2 * ln2^2 (S in exp2 domain)

  // ---- staging offsets (512 threads cooperate; u16 elements) ----
  // K [64][256]: 4 instrs; row = it*16+(tid>>5); chunk slot=(tid&31)^(row&31)
  int koff[4];
#pragma unroll
  for (int it = 0; it < 4; ++it) {
    int row = it * 16 + (tid >> 5);
    int ch  = (tid & 31) ^ (row & 31);
    koff[it] = row * CDIM + ch * 8;
  }
  // V [256][64]: 4 instrs; vr = it*64+(tid>>3); chunk slot=(tid&7)^(vr&7)
  int voff[4];
#pragma unroll
  for (int it = 0; it < 4; ++it) {
    int vr = it * 64 + (tid >> 3);
    int g8 = (tid & 7) ^ (vr & 7);
    voff[it] = vr * NTOK + g8 * 8;
  }

  u16* k2a = (u16*)smem;                 // 16384 u16 each
  u16* k2b = k2a + 16384;
  u16* v2a = (u16*)(smem + 65536);
  u16* v2b = v2a + 16384;

  auto stageK = [&](int n1, u16* dst) {
    const u16* kgb = K + (size_t)n1 * CDIM;
#pragma unroll
    for (int it = 0; it < 4; ++it)
      gload_lds16(kgb + koff[it], dst + it * 4096 + (tid >> 6) * 512 + lane * 8);
  };
  auto stageV = [&](int n1, u16* dst) {
    const u16* vgb = Vt + n1;
#pragma unroll
    for (int it = 0; it < 4; ++it)
      gload_lds16(vgb + voff[it], dst + it * 4096 + (tid >> 6) * 512 + lane * 8);
  };

  // prologue: tile 0 staged, full drain
  stageK(0, k2a);
  stageV(0, v2a);
  __syncthreads();                        // barrier A

  if (isProd) {
    // ---------------- producer path (waves 0,1,4,5) ----------------
    bf16x8 ones;
#pragma unroll
    for (int i = 0; i < 8; ++i) ones[i] = (short)0x3F80;

    bf16x8 aq[2][8];
#pragma unroll
    for (int g = 0; g < 2; ++g)
#pragma unroll
      for (int kk = 0; kk < 8; ++kk)
        aq[g][kk] = *(const bf16x8*)&Q[(size_t)(q0 + qh * 32 + g * 16 + col) * CDIM +
                                       kk * 32 + quad * 8];
    f32x4 lac[2];
    lac[0] = (f32x4){0.f, 0.f, 0.f, 0.f};
    lac[1] = (f32x4){0.f, 0.f, 0.f, 0.f};

    for (int t = 0; t < 64; ++t) {
      if (t < 63) {
        stageK((t + 1) * 64, (t & 1) ? k2a : k2b);
        stageV((t + 1) * 64, (t & 1) ? v2a : v2b);
      }
      const u16* ksrc = (t & 1) ? k2b : k2a;
      // S(t): 32 q (both groups) x this wave's 32 keys
      f32x4 s00 = (f32x4){0.f,0.f,0.f,0.f}, s10 = (f32x4){0.f,0.f,0.f,0.f};
      f32x4 s01 = (f32x4){0.f,0.f,0.f,0.f}, s11 = (f32x4){0.f,0.f,0.f,0.f};
      {
        int kr = kh * 32 + col;            // key 16-group j=0
        bf16x8 bk[8];
#pragma unroll
        for (int kk = 0; kk < 8; ++kk)
          bk[kk] = *(const bf16x8*)&ksrc[(size_t)kr * 256 + (((kk * 4 + quad) ^ (kr & 31)) & 31) * 8];
        __builtin_amdgcn_s_setprio(1);
#pragma unroll
        for (int kk = 0; kk < 8; ++kk) {
          s00 = __builtin_amdgcn_mfma_f32_16x16x32_bf16(aq[0][kk], bk[kk], s00, 0, 0, 0);
          s10 = __builtin_amdgcn_mfma_f32_16x16x32_bf16(aq[1][kk], bk[kk], s10, 0, 0, 0);
        }
        __builtin_amdgcn_s_setprio(0);
      }
      {
        int kr = kh * 32 + 16 + col;       // key 16-group j=1
        bf16x8 bk[8];
#pragma unroll
        for (int kk = 0; kk < 8; ++kk)
          bk[kk] = *(const bf16x8*)&ksrc[(size_t)kr * 256 + (((kk * 4 + quad) ^ (kr & 31)) & 31) * 8];
        __builtin_amdgcn_s_setprio(1);
#pragma unroll
        for (int kk = 0; kk < 8; ++kk) {
          s01 = __builtin_amdgcn_mfma_f32_16x16x32_bf16(aq[0][kk], bk[kk], s01, 0, 0, 0);
          s11 = __builtin_amdgcn_mfma_f32_16x16x32_bf16(aq[1][kk], bk[kk], s11, 0, 0, 0);
        }
        __builtin_amdgcn_s_setprio(0);
      }
      // P1 = exp2(s-64), P2 = relu(s)^2  (fixed-shift, exact; R10-verified)
      {
        int k0 = kh * 32 + col, k1 = k0 + 16;
#pragma unroll
        for (int r = 0; r < 4; ++r) {
          int qa = (qh * 32 + quad * 4 + r) * 72;
          int qb2 = qa + 16 * 72;
          float v;
          v = s00[r]; p1[qa + k0] = f2bf(fexp2(v - 64.f)); p2[qa + k0] = f2bf(v > 0.f ? v * v : 0.f);
          v = s01[r]; p1[qa + k1] = f2bf(fexp2(v - 64.f)); p2[qa + k1] = f2bf(v > 0.f ? v * v : 0.f);
          v = s10[r]; p1[qb2 + k0] = f2bf(fexp2(v - 64.f)); p2[qb2 + k0] = f2bf(v > 0.f ? v * v : 0.f);
          v = s11[r]; p1[qb2 + k1] = f2bf(fexp2(v - 64.f)); p2[qb2 + k1] = f2bf(v > 0.f ? v * v : 0.f);
        }
      }
      barrier_lgkm();                      // P visible; staging stays in flight
      // l-accumulate own kh-half cells (k = kh*32 + quad*8 .. +8)
#pragma unroll
      for (int g = 0; g < 2; ++g) {
        bf16x8 paf = *(const bf16x8*)&p1[(size_t)(qh * 32 + g * 16 + col) * 72 +
                                         kh * 32 + quad * 8];
        lac[g] = __builtin_amdgcn_mfma_f32_16x16x32_bf16(paf, ones, lac[g], 0, 0, 0);
      }
      __syncthreads();                     // staging landed; P reuse safe
    }

    if (col == 0) {
#pragma unroll
      for (int g = 0; g < 2; ++g)
#pragma unroll
        for (int r = 0; r < 4; ++r)
          lmerge[kh * 64 + qh * 32 + g * 16 + quad * 4 + r] = lac[g][r];
    }
    __syncthreads();                       // barrier B
  } else {
    // ---------------- consumer path (waves 2,3,6,7) ----------------
    f32x4 o1[4][4], o2[4][4];
#pragma unroll
    for (int i = 0; i < 4; ++i)
#pragma unroll
      for (int j = 0; j < 4; ++j) {
        o1[i][j] = (f32x4){0.f, 0.f, 0.f, 0.f};
        o2[i][j] = (f32x4){0.f, 0.f, 0.f, 0.f};
      }

    for (int t = 0; t < 64; ++t) {
      if (t < 63) {
        stageK((t + 1) * 64, (t & 1) ? k2a : k2b);
        stageV((t + 1) * 64, (t & 1) ? v2a : v2b);
      }
      const u16* vsrc = (t & 1) ? v2b : v2a;
      // pre-read ks-half 0 of V(t) — overlaps producers' S phase
      bf16x8 bv0[4];
#pragma unroll
      for (int j = 0; j < 4; ++j) {
        int vr = c4 * 64 + j * 16 + col;
        bv0[j] = *(const bf16x8*)&vsrc[(size_t)vr * 64 + ((quad ^ (vr & 7)) & 7) * 8];
      }
      barrier_lgkm();                      // P(t) published
      __builtin_amdgcn_s_setprio(1);
#pragma unroll
      for (int i = 0; i < 4; ++i) {        // ks-half 0: keys 0..31
        bf16x8 pa1 = *(const bf16x8*)&p1[(size_t)(i * 16 + col) * 72 + quad * 8];
        bf16x8 pa2 = *(const bf16x8*)&p2[(size_t)(i * 16 + col) * 72 + quad * 8];
#pragma unroll
        for (int j = 0; j < 4; ++j) {
          o1[i][j] = __builtin_amdgcn_mfma_f32_16x16x32_bf16(pa1, bv0[j], o1[i][j], 0, 0, 0);
          o2[i][j] = __builtin_amdgcn_mfma_f32_16x16x32_bf16(pa2, bv0[j], o2[i][j], 0, 0, 0);
        }
      }
      bf16x8 bv1[4];
#pragma unroll
      for (int j = 0; j < 4; ++j) {
        int vr = c4 * 64 + j * 16 + col;
        bv1[j] = *(const bf16x8*)&vsrc[(size_t)vr * 64 + (((4 + quad) ^ (vr & 7)) & 7) * 8];
      }
#pragma unroll
      for (int i = 0; i < 4; ++i) {        // ks-half 1: keys 32..63
        bf16x8 pa1 = *(const bf16x8*)&p1[(size_t)(i * 16 + col) * 72 + 32 + quad * 8];
        bf16x8 pa2 = *(const bf16x8*)&p2[(size_t)(i * 16 + col) * 72 + 32 + quad * 8];
#pragma unroll
        for (int j = 0; j < 4; ++j) {
          o1[i][j] = __builtin_amdgcn_mfma_f32_16x16x32_bf16(pa1, bv1[j], o1[i][j], 0, 0, 0);
          o2[i][j] = __builtin_amdgcn_mfma_f32_16x16x32_bf16(pa2, bv1[j], o2[i][j], 0, 0, 0);
        }
      }
      __builtin_amdgcn_s_setprio(0);
      __syncthreads();
    }

    __syncthreads();                       // barrier B (lmerge published)

    // ---- epilogue compute: combine + residual -> otile ----
#pragma unroll
    for (int i = 0; i < 4; ++i) {
      float linv[4];
#pragma unroll
      for (int r = 0; r < 4; ++r) {
        int q = i * 16 + quad * 4 + r;
        linv[r] = a1 / (lmerge[q] + lmerge[64 + q]);
      }
#pragma unroll
      for (int j = 0; j < 4; ++j) {
        int c = c4 * 64 + j * 16 + col;
        float4 v4;
        float* vv = (float*)&v4;
#pragma unroll
        for (int r = 0; r < 4; ++r) {
          int row = i * 16 + quad * 4 + r;
          vv[r] = linv[r] * o1[i][j][r] + a2p * o2[i][j][r] +
                  bf2f(xng[((size_t)b * NTOK + q0 + row) * CDIM + c]);
        }
        *(float4*)&otile[(size_t)c * 68 + i * 16 + quad * 4] = v4;
      }
    }
  }
  __syncthreads();   // barrier C: otile complete, visible to all waves

#pragma unroll
  for (int it = 0; it < 8; ++it) {
    int c  = it * 32 + (tid >> 4);
    int n4 = tid & 15;
    *(float4*)&outg[((size_t)b * CDIM + c) * NTOK + q0 + n4 * 4] =
        *(const float4*)&otile[(size_t)c * 68 + n4 * 4];
  }
}

// ---------------------------------------------------------------------------
extern "C" void kernel_launch(void* const* d_in, const int* in_sizes, int n_in,
                              void* d_out, int out_size, void* d_ws, size_t ws_size,
                              hipStream_t stream) {
  const float* x     = (const float*)d_in[0];
  const float* gamma = (const float*)d_in[1];
  const float* beta  = (const float*)d_in[2];
  const float* Wq    = (const float*)d_in[3];
  const float* Wk    = (const float*)d_in[4];
  const float* Wv    = (const float*)d_in[5];
  const float* w1    = (const float*)d_in[6];
  const float* w2    = (const float*)d_in[7];
  float* out = (float*)d_out;

  char* ws = (char*)d_ws;
  size_t off = 0;
  u16* xn  = (u16*)(ws + off); off += (size_t)BATCH * NTOK * CDIM * 2;
  u16* WT3 = (u16*)(ws + off); off += (size_t)3 * CDIM * CDIM * 2;   // [768][256]
  u16* Qb  = (u16*)(ws + off); off += (size_t)BATCH * NTOK * CDIM * 2;
  u16* Kb  = (u16*)(ws + off); off += (size_t)BATCH * NTOK * CDIM * 2;
  u16* VT  = (u16*)(ws + off); off += (size_t)BATCH * NTOK * CDIM * 2;  // [b][c][n]

  // 1) LayerNorm -> xn bf16 [B*N, C]
  ln_kernel<<<dim3(BATCH * (NTOK / 32)), 256, 0, stream>>>(x, gamma, beta, xn);

  // 2) stacked transposed weights, one launch (z selects Wq/Wk/Wv)
  wt3_kernel<<<dim3(8, 8, 3), dim3(32, 8), 0, stream>>>(Wq, Wk, Wv, WT3);

  // 3) fused Q/K/V projection (one launch)
  qkv_kernel<<<dim3(12, 128), 256, 0, stream>>>(xn, WT3, Qb, Kb, VT);

  // 4) fused attention (one-pass fixed-shift softmax, KVBLK=64, 64 iters)
  fa_kernel<<<dim3(256), 512, 0, stream>>>(Qb, Kb, VT, xn, w1, w2, out);
}